// Round 1
// baseline (2305.165 us; speedup 1.0000x reference)
//
#include <hip/hip_runtime.h>
#include <cstddef>
#include <cstdint>

#define B_ 64
#define T_ 800
#define D_ 80
#define H_ 128
#define G_ 512   // 4*H
#define K_ 39

__device__ __forceinline__ float sigmoidf_(float x) {
  return 1.0f / (1.0f + __expf(-x));
}

// One workgroup per (batch, dir). 512 threads; thread r owns gate-row r
// (Wih row: 80 fp32, Whh row: 128 fp32, both register-resident).
// LDS holds x_t (broadcast), h_{t-1} (broadcast), gate preactivations.
__global__ __launch_bounds__(512, 2)
void lstm_kernel(const float* __restrict__ x,
                 const float* __restrict__ Wih_f, const float* __restrict__ Whh_f,
                 const float* __restrict__ bih_f, const float* __restrict__ bhh_f,
                 const float* __restrict__ Wih_b, const float* __restrict__ Whh_b,
                 const float* __restrict__ bih_b, const float* __restrict__ bhh_b,
                 float* __restrict__ h_f, float* __restrict__ h_b)
{
  const int b   = blockIdx.x & 63;
  const int dir = blockIdx.x >> 6;
  const float* Wih = dir ? Wih_b : Wih_f;
  const float* Whh = dir ? Whh_b : Whh_f;
  const float* bih = dir ? bih_b : bih_f;
  const float* bhh = dir ? bhh_b : bhh_f;
  float* hout = dir ? h_b : h_f;

  const int r = threadIdx.x;

  float wih[D_];
  float whh[H_];
  #pragma unroll
  for (int i = 0; i < D_; ++i) wih[i] = Wih[r * D_ + i];
  #pragma unroll
  for (int j = 0; j < H_; ++j) whh[j] = Whh[r * H_ + j];
  const float bias = bih[r] + bhh[r];

  __shared__ float xs[D_];
  __shared__ float hs[H_];
  __shared__ float gs[G_];

  if (r < H_) hs[r] = 0.0f;
  float c = 0.0f;   // cell state, meaningful for r < 128 only
  __syncthreads();

  const float* xb = x + (size_t)b * T_ * D_;
  float* hb = hout + (size_t)b * T_ * H_;

  for (int tt = 0; tt < T_; ++tt) {
    const int t = dir ? (T_ - 1 - tt) : tt;
    if (r < D_) xs[r] = xb[t * D_ + r];
    __syncthreads();                       // xs and hs ready

    float acc = bias;
    #pragma unroll
    for (int i = 0; i < D_; ++i) acc += wih[i] * xs[i];
    #pragma unroll
    for (int j = 0; j < H_; ++j) acc += whh[j] * hs[j];
    gs[r] = acc;
    __syncthreads();                       // gs ready; all hs reads done

    if (r < H_) {
      float gi = gs[r];
      float gf = gs[H_ + r];
      float gg = gs[2 * H_ + r];
      float go = gs[3 * H_ + r];
      c = sigmoidf_(gf) * c + sigmoidf_(gi) * tanhf(gg);
      float h = sigmoidf_(go) * tanhf(c);
      hs[r] = h;
      hb[t * H_ + r] = h;
    }
    __syncthreads();                       // hs ready for next step
  }
}

// emissions[b,t,k] = bp[k] + Wp[k,0:128]·h_f[b,t] + Wp[k,128:256]·h_b[b,t]
// One 64-thread block per (b,t).
__global__ void emis_kernel(const float* __restrict__ h_f, const float* __restrict__ h_b,
                            const float* __restrict__ Wp, const float* __restrict__ bp,
                            float* __restrict__ em)
{
  const int bt  = blockIdx.x;   // b*T + t
  const int tid = threadIdx.x;  // 0..63
  __shared__ float hsh[2 * H_];
  const float2* hf2 = (const float2*)(h_f + (size_t)bt * H_);
  const float2* hb2 = (const float2*)(h_b + (size_t)bt * H_);
  float2 a  = hf2[tid];
  float2 bb = hb2[tid];
  hsh[2 * tid]          = a.x;  hsh[2 * tid + 1]      = a.y;
  hsh[H_ + 2 * tid]     = bb.x; hsh[H_ + 2 * tid + 1] = bb.y;
  __syncthreads();
  if (tid < K_) {
    const float* w = Wp + tid * 2 * H_;
    float acc = bp[tid];
    #pragma unroll 8
    for (int j = 0; j < 2 * H_; ++j) acc += w[j] * hsh[j];
    em[(size_t)bt * K_ + tid] = acc;
  }
}

// Numerator: parallel masked reduction over t per batch element.
__global__ void crf_num_kernel(const int* __restrict__ labels, const int* __restrict__ lengths,
                               const float* __restrict__ em,
                               const float* __restrict__ start_t, const float* __restrict__ end_t,
                               const float* __restrict__ trans,
                               float* __restrict__ num)
{
  const int b = blockIdx.x;
  const int tid = threadIdx.x;   // 256 threads
  const int len = lengths[b];
  float acc = 0.0f;
  for (int t = 1 + tid; t < len; t += 256) {
    int lp = labels[b * T_ + t - 1];
    int lc = labels[b * T_ + t];
    acc += trans[lp * K_ + lc] + em[((size_t)b * T_ + t) * K_ + lc];
  }
  __shared__ float red[256];
  red[tid] = acc;
  __syncthreads();
  for (int s = 128; s > 0; s >>= 1) {
    if (tid < s) red[tid] += red[tid + s];
    __syncthreads();
  }
  if (tid == 0) {
    int l0 = labels[b * T_];
    int ll = labels[b * T_ + len - 1];
    num[b] = red[0] + start_t[l0] + em[(size_t)b * T_ * K_ + l0] + end_t[ll];
  }
}

// Denominator: forward algorithm, one wave per batch element, early exit at len.
__global__ void crf_den_kernel(const float* __restrict__ em, const int* __restrict__ lengths,
                               const float* __restrict__ start_t, const float* __restrict__ end_t,
                               const float* __restrict__ trans,
                               float* __restrict__ den)
{
  const int b = blockIdx.x;
  const int tid = threadIdx.x;   // 64 threads (1 wave)
  __shared__ float tr[K_ * K_];
  __shared__ float alpha[K_];
  for (int i = tid; i < K_ * K_; i += 64) tr[i] = trans[i];
  if (tid < K_) alpha[tid] = start_t[tid] + em[(size_t)b * T_ * K_ + tid];
  const int len = lengths[b];
  __syncthreads();

  for (int t = 1; t < len; ++t) {
    float v = 0.0f;
    if (tid < K_) {
      float tmp[K_];
      float m = -1e30f;
      #pragma unroll
      for (int j = 0; j < K_; ++j) {
        tmp[j] = alpha[j] + tr[j * K_ + tid];
        m = fmaxf(m, tmp[j]);
      }
      float s = 0.0f;
      #pragma unroll
      for (int j = 0; j < K_; ++j) s += __expf(tmp[j] - m);
      v = m + __logf(s) + em[((size_t)b * T_ + t) * K_ + tid];
    }
    __syncthreads();
    if (tid < K_) alpha[tid] = v;
    __syncthreads();
  }

  if (tid == 0) {
    float m = -1e30f;
    for (int k = 0; k < K_; ++k) m = fmaxf(m, alpha[k] + end_t[k]);
    float s = 0.0f;
    for (int k = 0; k < K_; ++k) s += __expf(alpha[k] + end_t[k] - m);
    den[b] = m + __logf(s);
  }
}

// out = mean(den - num) over the 64 batch elements (one wave).
__global__ void finalize_kernel(const float* __restrict__ num, const float* __restrict__ den,
                                float* __restrict__ out)
{
  const int tid = threadIdx.x;   // 64
  float v = den[tid] - num[tid];
  #pragma unroll
  for (int off = 32; off > 0; off >>= 1) v += __shfl_down(v, off);
  if (tid == 0) out[0] = v * (1.0f / 64.0f);
}

extern "C" void kernel_launch(void* const* d_in, const int* in_sizes, int n_in,
                              void* d_out, int out_size, void* d_ws, size_t ws_size,
                              hipStream_t stream)
{
  (void)in_sizes; (void)n_in; (void)out_size; (void)ws_size;
  const float* features = (const float*)d_in[0];
  const int*   lengths  = (const int*)d_in[1];
  const int*   labels   = (const int*)d_in[2];
  const float* Wih_f = (const float*)d_in[3];
  const float* Whh_f = (const float*)d_in[4];
  const float* bih_f = (const float*)d_in[5];
  const float* bhh_f = (const float*)d_in[6];
  const float* Wih_b = (const float*)d_in[7];
  const float* Whh_b = (const float*)d_in[8];
  const float* bih_b = (const float*)d_in[9];
  const float* bhh_b = (const float*)d_in[10];
  const float* Wp      = (const float*)d_in[11];
  const float* bp      = (const float*)d_in[12];
  const float* start_t = (const float*)d_in[13];
  const float* end_t   = (const float*)d_in[14];
  const float* trans   = (const float*)d_in[15];
  float* out = (float*)d_out;

  float* ws  = (float*)d_ws;
  float* h_f = ws;                             // B*T*H
  float* h_b = h_f + (size_t)B_ * T_ * H_;     // B*T*H
  float* em  = h_b + (size_t)B_ * T_ * H_;     // B*T*K
  float* num = em + (size_t)B_ * T_ * K_;      // B
  float* den = num + B_;                       // B

  hipLaunchKernelGGL(lstm_kernel, dim3(2 * B_), dim3(512), 0, stream,
                     features, Wih_f, Whh_f, bih_f, bhh_f,
                     Wih_b, Whh_b, bih_b, bhh_b, h_f, h_b);
  hipLaunchKernelGGL(emis_kernel, dim3(B_ * T_), dim3(64), 0, stream,
                     h_f, h_b, Wp, bp, em);
  hipLaunchKernelGGL(crf_num_kernel, dim3(B_), dim3(256), 0, stream,
                     labels, lengths, em, start_t, end_t, trans, num);
  hipLaunchKernelGGL(crf_den_kernel, dim3(B_), dim3(64), 0, stream,
                     em, lengths, start_t, end_t, trans, den);
  hipLaunchKernelGGL(finalize_kernel, dim3(1), dim3(64), 0, stream,
                     num, den, out);
}

// Round 2
// 1475.566 us; speedup vs baseline: 1.5622x; 1.5622x over previous
//
#include <hip/hip_runtime.h>
#include <cstddef>
#include <cstdint>

#define B_ 64
#define T_ 800
#define D_ 80
#define H_ 128
#define G_ 512   // 4*H
#define K_ 39

typedef _Float16 h2_t __attribute__((ext_vector_type(2)));

__device__ __forceinline__ float fdot2_(h2_t a, h2_t b, float c) {
#if __has_builtin(__builtin_amdgcn_fdot2)
  return __builtin_amdgcn_fdot2(a, b, c, false);
#else
  return c + (float)a.x * (float)b.x + (float)a.y * (float)b.y;
#endif
}

__device__ __forceinline__ float sigf_(float x) {
  return 1.0f / (1.0f + __expf(-x));
}
__device__ __forceinline__ float tanhf_(float x) {
  // 2/(1+e^{-2x}) - 1 : saturates correctly at +/-1 for large |x|
  return 2.0f / (1.0f + __expf(-2.0f * x)) - 1.0f;
}

// One WG per (batch, dir). 512 threads; thread r owns gate-row r with
// f16x2-packed weights register-resident (40 + 64 = 104 VGPRs).
// LDS: xs (80 halves), hs (128 halves), gs (512 fp32). All reads broadcast.
// h written interleaved: hcat[b][t][dir*128 + j].
__global__ __launch_bounds__(512, 2)
void lstm_kernel(const float* __restrict__ x,
                 const float* __restrict__ Wih_f, const float* __restrict__ Whh_f,
                 const float* __restrict__ bih_f, const float* __restrict__ bhh_f,
                 const float* __restrict__ Wih_b, const float* __restrict__ Whh_b,
                 const float* __restrict__ bih_b, const float* __restrict__ bhh_b,
                 float* __restrict__ hcat)
{
  const int b   = blockIdx.x & 63;
  const int dir = blockIdx.x >> 6;
  const float* Wih = dir ? Wih_b : Wih_f;
  const float* Whh = dir ? Whh_b : Whh_f;
  const float* bih = dir ? bih_b : bih_f;
  const float* bhh = dir ? bhh_b : bhh_f;

  const int r = threadIdx.x;

  // Pack weights to f16x2 in registers.
  h2_t wih2[D_ / 2];
  h2_t whh2[H_ / 2];
  {
    const float* wr = Wih + r * D_;
    #pragma unroll
    for (int i = 0; i < D_ / 2; ++i) {
      h2_t v; v.x = (_Float16)wr[2 * i]; v.y = (_Float16)wr[2 * i + 1];
      wih2[i] = v;
    }
    const float* hr = Whh + r * H_;
    #pragma unroll
    for (int j = 0; j < H_ / 2; ++j) {
      h2_t v; v.x = (_Float16)hr[2 * j]; v.y = (_Float16)hr[2 * j + 1];
      whh2[j] = v;
    }
  }
  const float bias = bih[r] + bhh[r];

  __shared__ alignas(16) _Float16 xs_h[D_];
  __shared__ alignas(16) _Float16 hs_h[H_];
  __shared__ float gs[G_];

  if (r < H_) hs_h[r] = (_Float16)0.0f;
  float c = 0.0f;

  const float* xb = x + (size_t)b * T_ * D_;
  float* hb = hcat + (size_t)b * T_ * (2 * H_) + dir * H_;

  const int t0 = dir ? (T_ - 1) : 0;
  if (r < D_) xs_h[r] = (_Float16)xb[t0 * D_ + r];
  __syncthreads();

  for (int tt = 0; tt < T_; ++tt) {
    const int t  = dir ? (T_ - 1 - tt) : tt;
    const int tn = dir ? (t - 1) : (t + 1);

    // Prefetch next x (threads 128..207, idle in the gate phase otherwise).
    float xn = 0.0f;
    if (tt + 1 < T_ && r >= 128 && r < 128 + D_) xn = xb[tn * D_ + (r - 128)];

    const h2_t* xs2 = (const h2_t*)xs_h;
    const h2_t* hs2 = (const h2_t*)hs_h;
    float a0 = bias, a1 = 0.0f, a2 = 0.0f, a3 = 0.0f;
    #pragma unroll
    for (int i = 0; i < D_ / 2; i += 4) {
      a0 = fdot2_(wih2[i],     xs2[i],     a0);
      a1 = fdot2_(wih2[i + 1], xs2[i + 1], a1);
      a2 = fdot2_(wih2[i + 2], xs2[i + 2], a2);
      a3 = fdot2_(wih2[i + 3], xs2[i + 3], a3);
    }
    #pragma unroll
    for (int j = 0; j < H_ / 2; j += 4) {
      a0 = fdot2_(whh2[j],     hs2[j],     a0);
      a1 = fdot2_(whh2[j + 1], hs2[j + 1], a1);
      a2 = fdot2_(whh2[j + 2], hs2[j + 2], a2);
      a3 = fdot2_(whh2[j + 3], hs2[j + 3], a3);
    }
    gs[r] = (a0 + a1) + (a2 + a3);
    __syncthreads();   // gs ready; xs/hs reads of this step done

    if (r < H_) {
      float gi = gs[r];
      float gf = gs[H_ + r];
      float gg = gs[2 * H_ + r];
      float go = gs[3 * H_ + r];
      c = sigf_(gf) * c + sigf_(gi) * tanhf_(gg);
      float h = sigf_(go) * tanhf_(c);
      hs_h[r] = (_Float16)h;
      hb[(size_t)t * (2 * H_) + r] = h;
    } else if (r < 128 + D_) {
      if (tt + 1 < T_) xs_h[r - 128] = (_Float16)xn;
    }
    __syncthreads();   // hs/xs ready for next step
  }
}

// Emissions: em[bt,k] = bp[k] + Wp[k,:]·hcat[bt,:]. 64 bt-rows per block.
// h tile staged in LDS with stride 257 (conflict-free lane=row reads),
// Wp staged in LDS (wave-uniform broadcast reads).
__global__ __launch_bounds__(256)
void emis_kernel(const float* __restrict__ hcat,
                 const float* __restrict__ Wp, const float* __restrict__ bp,
                 float* __restrict__ em)
{
  __shared__ float sh[64 * 257];
  __shared__ float swp[40 * 256];
  const int tid = threadIdx.x;

  for (int i = tid; i < K_ * 256; i += 256) swp[i] = Wp[i];

  const float4* src = (const float4*)(hcat + (size_t)blockIdx.x * 64 * 256);
  for (int i = tid; i < 64 * 64; i += 256) {
    float4 v = src[i];
    int row = i >> 6, col = (i & 63) * 4;
    float* d = &sh[row * 257 + col];
    d[0] = v.x; d[1] = v.y; d[2] = v.z; d[3] = v.w;
  }
  __syncthreads();

  const int row = tid & 63;
  const int kq  = tid >> 6;          // wave-uniform
  const float* hrow = &sh[row * 257];

  float accs[10];
  #pragma unroll
  for (int q = 0; q < 10; ++q) {
    int k = kq * 10 + q;
    accs[q] = (k < K_) ? bp[k] : 0.0f;
  }

  for (int j0 = 0; j0 < 256; j0 += 4) {
    float h0 = hrow[j0], h1 = hrow[j0 + 1], hh2 = hrow[j0 + 2], h3 = hrow[j0 + 3];
    #pragma unroll
    for (int q = 0; q < 10; ++q) {
      const float4 w = *(const float4*)&swp[(kq * 10 + q) * 256 + j0];
      accs[q] += h0 * w.x + h1 * w.y + hh2 * w.z + h3 * w.w;
    }
  }

  const size_t bt = (size_t)blockIdx.x * 64 + row;
  #pragma unroll
  for (int q = 0; q < 10; ++q) {
    int k = kq * 10 + q;
    if (k < K_) em[bt * K_ + k] = accs[q];
  }
}

// Numerator: parallel masked reduction over t per batch element.
__global__ void crf_num_kernel(const int* __restrict__ labels, const int* __restrict__ lengths,
                               const float* __restrict__ em,
                               const float* __restrict__ start_t, const float* __restrict__ end_t,
                               const float* __restrict__ trans,
                               float* __restrict__ num)
{
  const int b = blockIdx.x;
  const int tid = threadIdx.x;   // 256 threads
  const int len = lengths[b];
  float acc = 0.0f;
  for (int t = 1 + tid; t < len; t += 256) {
    int lp = labels[b * T_ + t - 1];
    int lc = labels[b * T_ + t];
    acc += trans[lp * K_ + lc] + em[((size_t)b * T_ + t) * K_ + lc];
  }
  __shared__ float red[256];
  red[tid] = acc;
  __syncthreads();
  for (int s = 128; s > 0; s >>= 1) {
    if (tid < s) red[tid] += red[tid + s];
    __syncthreads();
  }
  if (tid == 0) {
    int l0 = labels[b * T_];
    int ll = labels[b * T_ + len - 1];
    num[b] = red[0] + start_t[l0] + em[(size_t)b * T_ * K_ + l0] + end_t[ll];
  }
}

// Denominator: forward algorithm, one wave per batch element.
// Restructured: nxt[k] = m + log( sum_j exp(alpha_j - m) * exp(trans[j,k]) )
// with exp(trans) precomputed (step-invariant) and m = max_j alpha_j via
// lane shuffles. One exp + one log + 39 FMA per lane per step.
__global__ void crf_den_kernel(const float* __restrict__ em, const int* __restrict__ lengths,
                               const float* __restrict__ start_t, const float* __restrict__ end_t,
                               const float* __restrict__ trans,
                               float* __restrict__ den)
{
  const int b = blockIdx.x;
  const int k = threadIdx.x;     // 64 threads (1 wave)
  __shared__ float et[K_ * 40];  // et[j*40+k] = exp(trans[j][k])
  __shared__ float p[64];

  for (int i = k; i < K_ * K_; i += 64)
    et[(i / K_) * 40 + (i % K_)] = __expf(trans[i]);

  const int len = lengths[b];
  float alpha = (k < K_) ? (start_t[k] + em[(size_t)b * T_ * K_ + k]) : -1e30f;
  float em_c = 0.0f;
  if (k < K_ && len > 1) em_c = em[((size_t)b * T_ + 1) * K_ + k];
  __syncthreads();

  for (int t = 1; t < len; ++t) {
    // prefetch em for t+1
    float em_n = 0.0f;
    int tp = (t + 1 < len) ? (t + 1) : (len - 1);
    if (k < K_) em_n = em[((size_t)b * T_ + tp) * K_ + k];

    // m = max over lanes
    float m = alpha;
    #pragma unroll
    for (int off = 32; off > 0; off >>= 1) m = fmaxf(m, __shfl_xor(m, off));

    p[k] = __expf(alpha - m);   // lanes >= 39 contribute exp(-huge) = 0
    __syncthreads();

    if (k < K_) {
      float s0 = 0.0f, s1 = 0.0f, s2 = 0.0f, s3 = 0.0f;
      #pragma unroll
      for (int j = 0; j < 36; j += 4) {
        s0 += p[j]     * et[j * 40 + k];
        s1 += p[j + 1] * et[(j + 1) * 40 + k];
        s2 += p[j + 2] * et[(j + 2) * 40 + k];
        s3 += p[j + 3] * et[(j + 3) * 40 + k];
      }
      s0 += p[36] * et[36 * 40 + k];
      s1 += p[37] * et[37 * 40 + k];
      s2 += p[38] * et[38 * 40 + k];
      float s = (s0 + s1) + (s2 + s3);
      alpha = m + __logf(s) + em_c;
    }
    em_c = em_n;
    __syncthreads();
  }

  float v = (k < K_) ? (alpha + end_t[k]) : -1e30f;
  float m = v;
  #pragma unroll
  for (int off = 32; off > 0; off >>= 1) m = fmaxf(m, __shfl_xor(m, off));
  float e = (k < K_) ? __expf(v - m) : 0.0f;
  #pragma unroll
  for (int off = 32; off > 0; off >>= 1) e += __shfl_xor(e, off);
  if (k == 0) den[b] = m + __logf(e);
}

// out = mean(den - num) over the 64 batch elements (one wave).
__global__ void finalize_kernel(const float* __restrict__ num, const float* __restrict__ den,
                                float* __restrict__ out)
{
  const int tid = threadIdx.x;   // 64
  float v = den[tid] - num[tid];
  #pragma unroll
  for (int off = 32; off > 0; off >>= 1) v += __shfl_down(v, off);
  if (tid == 0) out[0] = v * (1.0f / 64.0f);
}

extern "C" void kernel_launch(void* const* d_in, const int* in_sizes, int n_in,
                              void* d_out, int out_size, void* d_ws, size_t ws_size,
                              hipStream_t stream)
{
  (void)in_sizes; (void)n_in; (void)out_size; (void)ws_size;
  const float* features = (const float*)d_in[0];
  const int*   lengths  = (const int*)d_in[1];
  const int*   labels   = (const int*)d_in[2];
  const float* Wih_f = (const float*)d_in[3];
  const float* Whh_f = (const float*)d_in[4];
  const float* bih_f = (const float*)d_in[5];
  const float* bhh_f = (const float*)d_in[6];
  const float* Wih_b = (const float*)d_in[7];
  const float* Whh_b = (const float*)d_in[8];
  const float* bih_b = (const float*)d_in[9];
  const float* bhh_b = (const float*)d_in[10];
  const float* Wp      = (const float*)d_in[11];
  const float* bp      = (const float*)d_in[12];
  const float* start_t = (const float*)d_in[13];
  const float* end_t   = (const float*)d_in[14];
  const float* trans   = (const float*)d_in[15];
  float* out = (float*)d_out;

  float* ws   = (float*)d_ws;
  float* hcat = ws;                                  // B*T*256
  float* em   = hcat + (size_t)B_ * T_ * 2 * H_;     // B*T*K
  float* num  = em + (size_t)B_ * T_ * K_;           // B
  float* den  = num + B_;                            // B

  hipLaunchKernelGGL(lstm_kernel, dim3(2 * B_), dim3(512), 0, stream,
                     features, Wih_f, Whh_f, bih_f, bhh_f,
                     Wih_b, Whh_b, bih_b, bhh_b, hcat);
  hipLaunchKernelGGL(emis_kernel, dim3(B_ * T_ / 64), dim3(256), 0, stream,
                     hcat, Wp, bp, em);
  hipLaunchKernelGGL(crf_num_kernel, dim3(B_), dim3(256), 0, stream,
                     labels, lengths, em, start_t, end_t, trans, num);
  hipLaunchKernelGGL(crf_den_kernel, dim3(B_), dim3(64), 0, stream,
                     em, lengths, start_t, end_t, trans, den);
  hipLaunchKernelGGL(finalize_kernel, dim3(1), dim3(64), 0, stream,
                     num, den, out);
}

// Round 3
// 1208.083 us; speedup vs baseline: 1.9081x; 1.2214x over previous
//
#include <hip/hip_runtime.h>
#include <cstddef>
#include <cstdint>

#define B_ 64
#define T_ 800
#define D_ 80
#define H_ 128
#define G_ 512   // 4*H
#define K_ 39

typedef _Float16 h2_t __attribute__((ext_vector_type(2)));

__device__ __forceinline__ float fdot2_(h2_t a, h2_t b, float c) {
#if __has_builtin(__builtin_amdgcn_fdot2)
  return __builtin_amdgcn_fdot2(a, b, c, false);
#else
  return c + (float)a.x * (float)b.x + (float)a.y * (float)b.y;
#endif
}

__device__ __forceinline__ float sigf_(float x) {
  return 1.0f / (1.0f + __expf(-x));
}
__device__ __forceinline__ float tanhf_(float x) {
  return 2.0f / (1.0f + __expf(-2.0f * x)) - 1.0f;
}

// ---------------------------------------------------------------------------
// xw[dir][bt][r] (f16) = sum_k x[bt][k] * Wih_dir[r][k]   (bias added later)
// Block: 256 threads, one (dir, 32-bt-row tile). W streamed through LDS in
// 64-row chunks so all global reads are coalesced float4.
// ---------------------------------------------------------------------------
__global__ __launch_bounds__(256)
void xw_kernel(const float* __restrict__ x,
               const float* __restrict__ Wih_f, const float* __restrict__ Wih_b,
               _Float16* __restrict__ xw)
{
  const int dir  = blockIdx.x & 1;
  const int tile = blockIdx.x >> 1;      // 0..1599
  const float* W = dir ? Wih_b : Wih_f;

  __shared__ float xs[32][84];           // 84*4 % 16 == 0 -> aligned float4
  __shared__ float ws[64][84];

  const int tid = threadIdx.x;
  const int bt0 = tile * 32;

  {
    const float4* src = (const float4*)(x + (size_t)bt0 * D_);
    for (int i = tid; i < 32 * 20; i += 256) {
      float4 v = src[i];
      *(float4*)&xs[i / 20][(i % 20) * 4] = v;
    }
  }

  const int row = tid & 31;
  const int rr  = tid >> 5;   // 0..7

  for (int rc = 0; rc < 8; ++rc) {
    __syncthreads();   // xs ready (rc==0) / previous chunk's compute done
    {
      const float4* wsrc = (const float4*)(W + (size_t)(rc * 64) * D_);
      for (int i = tid; i < 64 * 20; i += 256) {
        float4 v = wsrc[i];
        *(float4*)&ws[i / 20][(i % 20) * 4] = v;
      }
    }
    __syncthreads();

    float acc[8] = {0.f, 0.f, 0.f, 0.f, 0.f, 0.f, 0.f, 0.f};
    for (int kq = 0; kq < 20; ++kq) {
      float4 xv = *(const float4*)&xs[row][kq * 4];
      #pragma unroll
      for (int j = 0; j < 8; ++j) {
        float4 wv = *(const float4*)&ws[rr * 8 + j][kq * 4];
        acc[j] = fmaf(xv.x, wv.x, fmaf(xv.y, wv.y, fmaf(xv.z, wv.z, fmaf(xv.w, wv.w, acc[j]))));
      }
    }
    _Float16 o[8];
    #pragma unroll
    for (int j = 0; j < 8; ++j) o[j] = (_Float16)acc[j];
    _Float16* dst = xw + ((size_t)dir * B_ * T_ + bt0 + row) * G_ + rc * 64 + rr * 8;
    *(float4*)dst = *(const float4*)o;   // 16B aligned store
  }
}

// ---------------------------------------------------------------------------
// Recurrent LSTM. One WG per (b, dir): 256 threads, thread (u = tid&127,
// hi = tid>>7) owns gate rows (256*hi + u, 256*hi + 128 + u):
//   hi==0 -> i,f rows of unit u ; hi==1 -> g,o rows of unit u.
// Whh rows f16x2 register-resident (128 VGPRs). Gate exchange: hi==1 writes
// g,o (2 floats) to LDS; hi==0 runs the nonlinearity and owns c.
// USE_XW=1: x-projection read from precomputed xw (f16); else fused x-dots.
// h written f16 to hcat[b][t][dir*128+u].
// ---------------------------------------------------------------------------
template<int USE_XW>
__global__ __launch_bounds__(256, 1)
void lstm_kernel(const float* __restrict__ x,
                 const float* __restrict__ Wih_f, const float* __restrict__ Whh_f,
                 const float* __restrict__ bih_f, const float* __restrict__ bhh_f,
                 const float* __restrict__ Wih_b, const float* __restrict__ Whh_b,
                 const float* __restrict__ bih_b, const float* __restrict__ bhh_b,
                 const _Float16* __restrict__ xw,
                 _Float16* __restrict__ hcat)
{
  const int b   = blockIdx.x & 63;
  const int dir = blockIdx.x >> 6;
  const float* Whh = dir ? Whh_b : Whh_f;
  const float* Wih = dir ? Wih_b : Wih_f;
  const float* bih = dir ? bih_b : bih_f;
  const float* bhh = dir ? bhh_b : bhh_f;

  const int tid = threadIdx.x;      // 0..255
  const int u   = tid & 127;
  const int hi  = tid >> 7;
  const int r0  = hi * 256 + u;
  const int r1  = r0 + 128;

  h2_t w0[H_ / 2], w1[H_ / 2];
  #pragma unroll
  for (int j = 0; j < H_ / 2; ++j) {
    const float* a = Whh + (size_t)r0 * H_ + 2 * j;
    const float* d = Whh + (size_t)r1 * H_ + 2 * j;
    h2_t v0; v0.x = (_Float16)a[0]; v0.y = (_Float16)a[1]; w0[j] = v0;
    h2_t v1; v1.x = (_Float16)d[0]; v1.y = (_Float16)d[1]; w1[j] = v1;
  }
  h2_t wx0[D_ / 2], wx1[D_ / 2];
  if (!USE_XW) {
    #pragma unroll
    for (int i = 0; i < D_ / 2; ++i) {
      const float* a = Wih + (size_t)r0 * D_ + 2 * i;
      const float* d = Wih + (size_t)r1 * D_ + 2 * i;
      h2_t v0; v0.x = (_Float16)a[0]; v0.y = (_Float16)a[1]; wx0[i] = v0;
      h2_t v1; v1.x = (_Float16)d[0]; v1.y = (_Float16)d[1]; wx1[i] = v1;
    }
  }
  const float bias0 = bih[r0] + bhh[r0];
  const float bias1 = bih[r1] + bhh[r1];

  __shared__ _Float16 hs_h[H_];
  __shared__ float    go_s[2][H_];
  __shared__ _Float16 xs_h[D_];

  if (tid < H_) hs_h[tid] = (_Float16)0.0f;
  float c = 0.0f;

  const float*    xb  = x + (size_t)b * T_ * D_;
  const _Float16* xwb = xw + ((size_t)dir * B_ * T_ + (size_t)b * T_) * G_;
  _Float16*       hb  = hcat + (size_t)b * T_ * (2 * H_) + dir * H_;

  const int t0 = dir ? (T_ - 1) : 0;
  _Float16 xw0p = (_Float16)0.0f, xw1p = (_Float16)0.0f;
  if (USE_XW) {
    xw0p = xwb[(size_t)t0 * G_ + r0];
    xw1p = xwb[(size_t)t0 * G_ + r1];
  } else {
    if (tid < D_) xs_h[tid] = (_Float16)xb[t0 * D_ + tid];
  }
  __syncthreads();

  for (int tt = 0; tt < T_; ++tt) {
    const int t  = dir ? (T_ - 1 - tt) : tt;
    const int tn = dir ? (t - 1) : (t + 1);

    float a0 = bias0, a1 = bias1, b0 = 0.0f, b1 = 0.0f;
    float xn = 0.0f;
    if (USE_XW) {
      a0 += (float)xw0p;
      a1 += (float)xw1p;
      if (tt + 1 < T_) {         // prefetch next step's xw
        xw0p = xwb[(size_t)tn * G_ + r0];
        xw1p = xwb[(size_t)tn * G_ + r1];
      }
    } else {
      if (tt + 1 < T_ && tid >= 128 && tid < 128 + D_) xn = xb[tn * D_ + (tid - 128)];
      const h2_t* xs2 = (const h2_t*)xs_h;
      #pragma unroll
      for (int i = 0; i < D_ / 2; i += 2) {
        a0 = fdot2_(wx0[i],     xs2[i],     a0);
        b0 = fdot2_(wx0[i + 1], xs2[i + 1], b0);
        a1 = fdot2_(wx1[i],     xs2[i],     a1);
        b1 = fdot2_(wx1[i + 1], xs2[i + 1], b1);
      }
    }

    const h2_t* hs2 = (const h2_t*)hs_h;
    #pragma unroll
    for (int j = 0; j < H_ / 2; j += 2) {
      a0 = fdot2_(w0[j],     hs2[j],     a0);
      b0 = fdot2_(w0[j + 1], hs2[j + 1], b0);
      a1 = fdot2_(w1[j],     hs2[j],     a1);
      b1 = fdot2_(w1[j + 1], hs2[j + 1], b1);
    }
    const float g0 = a0 + b0;   // row r0 (i or g)
    const float g1 = a1 + b1;   // row r1 (f or o)

    if (hi) { go_s[0][u] = g0; go_s[1][u] = g1; }
    __syncthreads();           // g,o visible; hs reads of this step done

    if (!hi) {
      const float gi = g0, gf = g1;
      const float gg = go_s[0][u], go = go_s[1][u];
      c = sigf_(gf) * c + sigf_(gi) * tanhf_(gg);
      const float h = sigf_(go) * tanhf_(c);
      hs_h[u] = (_Float16)h;
      hb[(size_t)t * (2 * H_) + u] = (_Float16)h;
    } else if (!USE_XW) {
      if (tt + 1 < T_ && tid < 128 + D_) xs_h[tid - 128] = (_Float16)xn;
    }
    __syncthreads();           // new hs (and xs) ready
  }
}

// ---------------------------------------------------------------------------
// Emissions from f16 hcat. 64 bt-rows per block; h tile in LDS (stride 257),
// Wp in LDS (wave-uniform broadcast).
// ---------------------------------------------------------------------------
__global__ __launch_bounds__(256)
void emis_kernel(const _Float16* __restrict__ hcat,
                 const float* __restrict__ Wp, const float* __restrict__ bp,
                 float* __restrict__ em)
{
  __shared__ float sh[64 * 257];
  __shared__ float swp[40 * 256];
  const int tid = threadIdx.x;

  for (int i = tid; i < K_ * 256; i += 256) swp[i] = Wp[i];

  const h2_t* src = (const h2_t*)(hcat + (size_t)blockIdx.x * 64 * 256);
  for (int i = tid; i < 64 * 128; i += 256) {
    h2_t v = src[i];
    int row = i >> 7, col = (i & 127) * 2;
    sh[row * 257 + col]     = (float)v.x;
    sh[row * 257 + col + 1] = (float)v.y;
  }
  __syncthreads();

  const int row = tid & 63;
  const int kq  = tid >> 6;          // wave-uniform
  const float* hrow = &sh[row * 257];

  float accs[10];
  #pragma unroll
  for (int q = 0; q < 10; ++q) {
    int k = kq * 10 + q;
    accs[q] = (k < K_) ? bp[k] : 0.0f;
  }

  for (int j0 = 0; j0 < 256; j0 += 4) {
    float h0 = hrow[j0], h1 = hrow[j0 + 1], hh2 = hrow[j0 + 2], h3 = hrow[j0 + 3];
    #pragma unroll
    for (int q = 0; q < 10; ++q) {
      const float4 w = *(const float4*)&swp[(kq * 10 + q) * 256 + j0];
      accs[q] += h0 * w.x + h1 * w.y + hh2 * w.z + h3 * w.w;
    }
  }

  const size_t bt = (size_t)blockIdx.x * 64 + row;
  #pragma unroll
  for (int q = 0; q < 10; ++q) {
    int k = kq * 10 + q;
    if (k < K_) em[bt * K_ + k] = accs[q];
  }
}

// ---------------------------------------------------------------------------
// Numerator: masked reduction over t per batch element.
// ---------------------------------------------------------------------------
__global__ void crf_num_kernel(const int* __restrict__ labels, const int* __restrict__ lengths,
                               const float* __restrict__ em,
                               const float* __restrict__ start_t, const float* __restrict__ end_t,
                               const float* __restrict__ trans,
                               float* __restrict__ num)
{
  const int b = blockIdx.x;
  const int tid = threadIdx.x;   // 256
  const int len = lengths[b];
  float acc = 0.0f;
  for (int t = 1 + tid; t < len; t += 256) {
    int lp = labels[b * T_ + t - 1];
    int lc = labels[b * T_ + t];
    acc += trans[lp * K_ + lc] + em[((size_t)b * T_ + t) * K_ + lc];
  }
  __shared__ float red[256];
  red[tid] = acc;
  __syncthreads();
  for (int s = 128; s > 0; s >>= 1) {
    if (tid < s) red[tid] += red[tid + s];
    __syncthreads();
  }
  if (tid == 0) {
    int l0 = labels[b * T_];
    int ll = labels[b * T_ + len - 1];
    num[b] = red[0] + start_t[l0] + em[(size_t)b * T_ * K_ + l0] + end_t[ll];
  }
}

// ---------------------------------------------------------------------------
// Denominator: forward algorithm in LINEAR space, renormalized every 4 steps.
// One wave per batch element. M = exp(trans) column register-resident per
// lane (39 VGPRs). Per step: v'_k = (sum_j v_j * M[j][k]) * exp(em[t][k]).
// ---------------------------------------------------------------------------
__global__ void crf_den_kernel(const float* __restrict__ em, const int* __restrict__ lengths,
                               const float* __restrict__ start_t, const float* __restrict__ end_t,
                               const float* __restrict__ trans,
                               float* __restrict__ den)
{
  const int b = blockIdx.x;
  const int k = threadIdx.x;     // 64 threads = 1 wave
  __shared__ float p[64];

  float et[K_];
  #pragma unroll
  for (int j = 0; j < K_; ++j)
    et[j] = (k < K_) ? __expf(trans[j * K_ + k]) : 0.0f;

  const int len = lengths[b];
  const float* emb = em + (size_t)b * T_ * K_;

  float a0 = (k < K_) ? (start_t[k] + emb[k]) : -1e30f;
  float m = a0;
  #pragma unroll
  for (int off = 32; off > 0; off >>= 1) m = fmaxf(m, __shfl_xor(m, off));
  float v = __expf(a0 - m);           // lanes >= 39 -> 0
  float off_acc = m;
  p[k] = v;

  float emn = 0.0f;
  if (k < K_ && len > 1) emn = emb[K_ + k];
  __syncthreads();

  for (int t = 1; t < len; ++t) {
    const float emc = emn;
    const int tp = (t + 1 < len) ? (t + 1) : (len - 1);
    emn = (k < K_) ? emb[(size_t)tp * K_ + k] : 0.0f;   // prefetch

    float s0 = 0.f, s1 = 0.f, s2 = 0.f, s3 = 0.f;
    const float4* p4 = (const float4*)p;
    #pragma unroll
    for (int j4 = 0; j4 < 9; ++j4) {
      float4 pv = p4[j4];
      s0 = fmaf(pv.x, et[4 * j4 + 0], s0);
      s1 = fmaf(pv.y, et[4 * j4 + 1], s1);
      s2 = fmaf(pv.z, et[4 * j4 + 2], s2);
      s3 = fmaf(pv.w, et[4 * j4 + 3], s3);
    }
    s0 = fmaf(p[36], et[36], s0);
    s1 = fmaf(p[37], et[37], s1);
    s2 = fmaf(p[38], et[38], s2);
    float s = (s0 + s1) + (s2 + s3);

    v = s * __expf(emc);
    if ((t & 3) == 0) {               // renormalize every 4 steps
      float vm = v;
      #pragma unroll
      for (int off = 32; off > 0; off >>= 1) vm = fmaxf(vm, __shfl_xor(vm, off));
      float inv = 1.0f / vm;
      v *= inv;
      off_acc += __logf(vm);
    }
    __syncthreads();                  // all lanes done reading old p
    p[k] = v;
    __syncthreads();                  // new p visible
  }

  float w = (k < K_) ? v * __expf(end_t[k]) : 0.0f;
  #pragma unroll
  for (int off = 32; off > 0; off >>= 1) w += __shfl_xor(w, off);
  if (k == 0) den[b] = off_acc + __logf(w);
}

__global__ void finalize_kernel(const float* __restrict__ num, const float* __restrict__ den,
                                float* __restrict__ out)
{
  const int tid = threadIdx.x;   // 64
  float v = den[tid] - num[tid];
  #pragma unroll
  for (int off = 32; off > 0; off >>= 1) v += __shfl_down(v, off);
  if (tid == 0) out[0] = v * (1.0f / 64.0f);
}

extern "C" void kernel_launch(void* const* d_in, const int* in_sizes, int n_in,
                              void* d_out, int out_size, void* d_ws, size_t ws_size,
                              hipStream_t stream)
{
  (void)in_sizes; (void)n_in; (void)out_size;
  const float* features = (const float*)d_in[0];
  const int*   lengths  = (const int*)d_in[1];
  const int*   labels   = (const int*)d_in[2];
  const float* Wih_f = (const float*)d_in[3];
  const float* Whh_f = (const float*)d_in[4];
  const float* bih_f = (const float*)d_in[5];
  const float* bhh_f = (const float*)d_in[6];
  const float* Wih_b = (const float*)d_in[7];
  const float* Whh_b = (const float*)d_in[8];
  const float* bih_b = (const float*)d_in[9];
  const float* bhh_b = (const float*)d_in[10];
  const float* Wp      = (const float*)d_in[11];
  const float* bp      = (const float*)d_in[12];
  const float* start_t = (const float*)d_in[13];
  const float* end_t   = (const float*)d_in[14];
  const float* trans   = (const float*)d_in[15];
  float* out = (float*)d_out;

  // ws layout (bytes):
  //   hcat f16 : 0        .. 26,214,400
  //   em   f32 : 26214400 .. +7,987,200
  //   num/den  : 512 B
  //   xw   f16 : 34202112 .. +104,857,600   (only if ws is big enough)
  char* wsc = (char*)d_ws;
  _Float16* hcatH = (_Float16*)wsc;
  float*    em    = (float*)(wsc + 26214400);
  float*    num   = (float*)(wsc + 26214400 + 7987200);
  float*    den   = num + B_;
  _Float16* xwH   = (_Float16*)(wsc + 34202112);
  const bool big  = ws_size >= (size_t)34202112 + 104857600;

  if (big) {
    hipLaunchKernelGGL(xw_kernel, dim3(3200), dim3(256), 0, stream,
                       features, Wih_f, Wih_b, xwH);
    hipLaunchKernelGGL((lstm_kernel<1>), dim3(2 * B_), dim3(256), 0, stream,
                       features, Wih_f, Whh_f, bih_f, bhh_f,
                       Wih_b, Whh_b, bih_b, bhh_b, xwH, hcatH);
  } else {
    hipLaunchKernelGGL((lstm_kernel<0>), dim3(2 * B_), dim3(256), 0, stream,
                       features, Wih_f, Whh_f, bih_f, bhh_f,
                       Wih_b, Whh_b, bih_b, bhh_b, xwH, hcatH);
  }
  hipLaunchKernelGGL(emis_kernel, dim3(B_ * T_ / 64), dim3(256), 0, stream,
                     hcatH, Wp, bp, em);
  hipLaunchKernelGGL(crf_num_kernel, dim3(B_), dim3(256), 0, stream,
                     labels, lengths, em, start_t, end_t, trans, num);
  hipLaunchKernelGGL(crf_den_kernel, dim3(B_), dim3(64), 0, stream,
                     em, lengths, start_t, end_t, trans, den);
  hipLaunchKernelGGL(finalize_kernel, dim3(1), dim3(64), 0, stream,
                     num, den, out);
}